// Round 2
// 4167.761 us; speedup vs baseline: 3.3296x; 3.3296x over previous
//
#include <hip/hip_runtime.h>
#include <cmath>

#define NPTS  200000
#define KNBR  16
#define MROWS 3200000   // NPTS*KNBR
#define EPSB  1e-5f

__device__ __forceinline__ float gelu_f(float x) {
    return 0.5f * x * (1.0f + erff(x * 0.70710678118654752f));
}

// ---------------- stats over y1 = x @ w1 (16 ch) ----------------
__global__ __launch_bounds__(256) void k_stats1(
    const float* __restrict__ p, const float4* __restrict__ f,
    const int* __restrict__ gidx, const float* __restrict__ w1,
    float* __restrict__ stats)
{
    __shared__ float w1s[112];
    __shared__ float red[4 * 32];
    for (int i = threadIdx.x; i < 112; i += 256) w1s[i] = w1[i];
    __syncthreads();

    float acc[32];
#pragma unroll
    for (int c = 0; c < 32; c++) acc[c] = 0.f;

    int stride = gridDim.x * 256;
    for (int r = blockIdx.x * 256 + threadIdx.x; r < MROWS; r += stride) {
        int n = r >> 4;
        int idx = gidx[r];
        float4 fv = f[idx];
        float x[7];
        x[0] = p[idx * 3 + 0] - p[n * 3 + 0];
        x[1] = p[idx * 3 + 1] - p[n * 3 + 1];
        x[2] = p[idx * 3 + 2] - p[n * 3 + 2];
        x[3] = fv.x; x[4] = fv.y; x[5] = fv.z; x[6] = fv.w;
#pragma unroll
        for (int j = 0; j < 16; j++) {
            float y = 0.f;
#pragma unroll
            for (int i = 0; i < 7; i++) y = fmaf(x[i], w1s[i * 16 + j], y);
            acc[j] += y;
            acc[16 + j] += y * y;
        }
    }
    int lane = threadIdx.x & 63, wv = threadIdx.x >> 6;
#pragma unroll
    for (int c = 0; c < 32; c++) {
        float v = acc[c];
        v += __shfl_down(v, 32); v += __shfl_down(v, 16); v += __shfl_down(v, 8);
        v += __shfl_down(v, 4);  v += __shfl_down(v, 2);  v += __shfl_down(v, 1);
        if (lane == 0) red[wv * 32 + c] = v;
    }
    __syncthreads();
    for (int c = threadIdx.x; c < 32; c += 256)
        atomicAdd(&stats[c], red[c] + red[32 + c] + red[64 + c] + red[96 + c]);
}

// ---------------- stats over y2 = gelu(bn(y1)) @ w2 (32 ch) ----------------
__global__ __launch_bounds__(256) void k_stats2(
    const float* __restrict__ p, const float4* __restrict__ f,
    const int* __restrict__ gidx, const float* __restrict__ w1,
    const float* __restrict__ w2, const float* __restrict__ scsh1,
    float* __restrict__ stats)
{
    __shared__ float w1s[112];
    __shared__ float w2s[512];
    __shared__ float sc1s[16], sh1s[16];
    __shared__ float red[4 * 64];
    for (int i = threadIdx.x; i < 112; i += 256) w1s[i] = w1[i];
    for (int i = threadIdx.x; i < 512; i += 256) w2s[i] = w2[i];
    if (threadIdx.x < 16) {
        sc1s[threadIdx.x] = scsh1[threadIdx.x];
        sh1s[threadIdx.x] = scsh1[16 + threadIdx.x];
    }
    __syncthreads();

    float acc[64];
#pragma unroll
    for (int c = 0; c < 64; c++) acc[c] = 0.f;

    int stride = gridDim.x * 256;
    for (int r = blockIdx.x * 256 + threadIdx.x; r < MROWS; r += stride) {
        int n = r >> 4;
        int idx = gidx[r];
        float4 fv = f[idx];
        float x[7];
        x[0] = p[idx * 3 + 0] - p[n * 3 + 0];
        x[1] = p[idx * 3 + 1] - p[n * 3 + 1];
        x[2] = p[idx * 3 + 2] - p[n * 3 + 2];
        x[3] = fv.x; x[4] = fv.y; x[5] = fv.z; x[6] = fv.w;
        float h1[16];
#pragma unroll
        for (int j = 0; j < 16; j++) {
            float y = 0.f;
#pragma unroll
            for (int i = 0; i < 7; i++) y = fmaf(x[i], w1s[i * 16 + j], y);
            h1[j] = gelu_f(fmaf(y, sc1s[j], sh1s[j]));
        }
#pragma unroll
        for (int j = 0; j < 32; j++) {
            float y = 0.f;
#pragma unroll
            for (int i = 0; i < 16; i++) y = fmaf(h1[i], w2s[i * 32 + j], y);
            acc[j] += y;
            acc[32 + j] += y * y;
        }
    }
    int lane = threadIdx.x & 63, wv = threadIdx.x >> 6;
#pragma unroll
    for (int c = 0; c < 64; c++) {
        float v = acc[c];
        v += __shfl_down(v, 32); v += __shfl_down(v, 16); v += __shfl_down(v, 8);
        v += __shfl_down(v, 4);  v += __shfl_down(v, 2);  v += __shfl_down(v, 1);
        if (lane == 0) red[wv * 64 + c] = v;
    }
    __syncthreads();
    for (int c = threadIdx.x; c < 64; c += 256)
        atomicAdd(&stats[c], red[c] + red[64 + c] + red[128 + c] + red[192 + c]);
}

// BN finalize: scale/shift from sum/sumsq
__global__ void k_finalize(const float* __restrict__ stats, const float* __restrict__ g,
                           const float* __restrict__ b, float* __restrict__ scsh,
                           int H, float invM)
{
    int j = threadIdx.x;
    if (j < H) {
        float m = stats[j] * invM;
        float v = stats[H + j] * invM - m * m;
        float sc = g[j] * rsqrtf(v + EPSB);
        scsh[j] = sc;
        scsh[H + j] = fmaf(-m, sc, b[j]);
    }
}

// ---------------- full MLP, row-per-thread; max-pool over K via 16-lane
// shfl butterfly; each lane retains 4 of 64 pooled channels (lane&15 picks
// the chunk) -> pooled regs = 4 not 64, no spills.
// Grid: 3125 blocks * 256 thr * 4 iters == 3,200,000 rows exactly (no tail).
__global__ __launch_bounds__(256, 4) void k_pool2(
    const float* __restrict__ p, const float4* __restrict__ f,
    const int* __restrict__ gidx,
    const float* __restrict__ w1, const float* __restrict__ w2,
    const float* __restrict__ w3,
    const float* __restrict__ scsh1, const float* __restrict__ scsh2,
    float* __restrict__ stats, float* __restrict__ pooled)
{
    __shared__ float w1s[112];
    __shared__ float w2s[512];
    __shared__ float w3s[2048];
    __shared__ float sc1s[16], sh1s[16], sc2s[32], sh2s[32];
    __shared__ float reds[256];
    __shared__ float redq[256];
    int tid = threadIdx.x;
    for (int i = tid; i < 112; i += 256) w1s[i] = w1[i];
    for (int i = tid; i < 512; i += 256) w2s[i] = w2[i];
    for (int i = tid; i < 2048; i += 256) w3s[i] = w3[i];
    if (tid < 16) { sc1s[tid] = scsh1[tid]; sh1s[tid] = scsh1[16 + tid]; }
    if (tid < 32) { sc2s[tid] = scsh2[tid]; sh2s[tid] = scsh2[32 + tid]; }
    __syncthreads();

    int lane = tid & 63;
    int sub  = lane & 15;   // this lane keeps channels [4*sub, 4*sub+3]

    float s0 = 0.f, s1 = 0.f, s2 = 0.f, s3 = 0.f;
    float q0 = 0.f, q1 = 0.f, q2 = 0.f, q3 = 0.f;

    const int stride = 3125 * 256;  // 800000
#pragma unroll 1
    for (int r = blockIdx.x * 256 + tid; r < MROWS; r += stride) {
        int n = r >> 4;                 // point; its 16 rows sit in 16 consecutive lanes
        int idx = gidx[r];              // fully coalesced
        float4 fv = f[idx];
        float x[7];
        x[0] = p[idx * 3 + 0] - p[n * 3 + 0];
        x[1] = p[idx * 3 + 1] - p[n * 3 + 1];
        x[2] = p[idx * 3 + 2] - p[n * 3 + 2];
        x[3] = fv.x; x[4] = fv.y; x[5] = fv.z; x[6] = fv.w;

        float h1[16];
#pragma unroll
        for (int j = 0; j < 16; j++) {
            float y = 0.f;
#pragma unroll
            for (int i = 0; i < 7; i++) y = fmaf(x[i], w1s[i * 16 + j], y);
            h1[j] = gelu_f(fmaf(y, sc1s[j], sh1s[j]));
        }
        float h2[32];
#pragma unroll
        for (int j = 0; j < 32; j++) {
            float y = 0.f;
#pragma unroll
            for (int i = 0; i < 16; i++) y = fmaf(h1[i], w2s[i * 32 + j], y);
            h2[j] = gelu_f(fmaf(y, sc2s[j], sh2s[j]));
        }

        float pv0 = 0.f, pv1 = 0.f, pv2 = 0.f, pv3 = 0.f;
#pragma unroll
        for (int c = 0; c < 16; c++) {
            float y0 = 0.f, y1 = 0.f, y2 = 0.f, y3 = 0.f;
#pragma unroll
            for (int i = 0; i < 32; i++) {
                float h = h2[i];
                const float* wp = &w3s[i * 64 + c * 4];   // wave-uniform -> LDS broadcast
                y0 = fmaf(h, wp[0], y0);
                y1 = fmaf(h, wp[1], y1);
                y2 = fmaf(h, wp[2], y2);
                y3 = fmaf(h, wp[3], y3);
            }
            // max over the point's 16 rows (lanes l0..l0+15)
#pragma unroll
            for (int m = 1; m <= 8; m <<= 1) {
                y0 = fmaxf(y0, __shfl_xor(y0, m));
                y1 = fmaxf(y1, __shfl_xor(y1, m));
                y2 = fmaxf(y2, __shfl_xor(y2, m));
                y3 = fmaxf(y3, __shfl_xor(y3, m));
            }
            if (sub == c) { pv0 = y0; pv1 = y1; pv2 = y2; pv3 = y3; }
        }
        // 16 lanes cover point n's 64 channels contiguously -> coalesced
        *(float4*)&pooled[(size_t)n * 64 + sub * 4] = make_float4(pv0, pv1, pv2, pv3);
        s0 += pv0; q0 = fmaf(pv0, pv0, q0);
        s1 += pv1; q1 = fmaf(pv1, pv1, q1);
        s2 += pv2; q2 = fmaf(pv2, pv2, q2);
        s3 += pv3; q3 = fmaf(pv3, pv3, q3);
    }

    // fold lanes l+16,l+32,l+48 into lanes 0..15 (same channel set)
    s0 += __shfl_down(s0, 32); s0 += __shfl_down(s0, 16);
    s1 += __shfl_down(s1, 32); s1 += __shfl_down(s1, 16);
    s2 += __shfl_down(s2, 32); s2 += __shfl_down(s2, 16);
    s3 += __shfl_down(s3, 32); s3 += __shfl_down(s3, 16);
    q0 += __shfl_down(q0, 32); q0 += __shfl_down(q0, 16);
    q1 += __shfl_down(q1, 32); q1 += __shfl_down(q1, 16);
    q2 += __shfl_down(q2, 32); q2 += __shfl_down(q2, 16);
    q3 += __shfl_down(q3, 32); q3 += __shfl_down(q3, 16);
    int wv = tid >> 6;
    if (lane < 16) {
        reds[wv * 64 + sub * 4 + 0] = s0;
        reds[wv * 64 + sub * 4 + 1] = s1;
        reds[wv * 64 + sub * 4 + 2] = s2;
        reds[wv * 64 + sub * 4 + 3] = s3;
        redq[wv * 64 + sub * 4 + 0] = q0;
        redq[wv * 64 + sub * 4 + 1] = q1;
        redq[wv * 64 + sub * 4 + 2] = q2;
        redq[wv * 64 + sub * 4 + 3] = q3;
    }
    __syncthreads();
    if (tid < 64) {
        atomicAdd(&stats[tid],
                  reds[tid] + reds[64 + tid] + reds[128 + tid] + reds[192 + tid]);
        atomicAdd(&stats[64 + tid],
                  redq[tid] + redq[64 + tid] + redq[128 + tid] + redq[192 + tid]);
    }
}

// double-BN collapse: z = a1*(y-m)+b_nbr has mean b_nbr, var a1^2*v exactly
__global__ void k_fin3(const float* __restrict__ stats,
                       const float* __restrict__ g_nbr, const float* __restrict__ g_post,
                       const float* __restrict__ b_post, float* __restrict__ scsh)
{
    int j = threadIdx.x;
    if (j < 64) {
        float m = stats[j] * (1.0f / NPTS);
        float v = stats[64 + j] * (1.0f / NPTS) - m * m;
        float a1 = g_nbr[j] * rsqrtf(v + EPSB);
        float s3 = g_post[j] * a1 * rsqrtf(fmaf(a1 * a1, v, EPSB));
        scsh[j] = s3;
        scsh[64 + j] = fmaf(-m, s3, b_post[j]);
    }
}

// ---------------- head: (N x 64) @ (64 x 256) ----------------
__global__ __launch_bounds__(256) void k_head(
    const float* __restrict__ pooled, const float* __restrict__ scsh3,
    const float* __restrict__ wpost, float* __restrict__ out)
{
    __shared__ float rowbuf[512];
    __shared__ float s3s[64], c3s[64];
    int tid = threadIdx.x;
    if (tid < 64) { s3s[tid] = scsh3[tid]; c3s[tid] = scsh3[64 + tid]; }
    float wcol[64];
#pragma unroll
    for (int j = 0; j < 64; j++) wcol[j] = wpost[j * 256 + tid];
    __syncthreads();

    const int nchunks = NPTS / 8;  // 25000
    for (int c = blockIdx.x; c < nchunks; c += gridDim.x) {
        int n0 = c * 8;
#pragma unroll
        for (int t = tid; t < 512; t += 256) {
            int rr = t >> 6, j = t & 63;
            rowbuf[t] = fmaf(pooled[(size_t)(n0 + rr) * 64 + j], s3s[j], c3s[j]);
        }
        __syncthreads();
#pragma unroll
        for (int rr = 0; rr < 8; rr++) {
            float acc = 0.f;
#pragma unroll
            for (int j = 0; j < 64; j++) acc = fmaf(rowbuf[rr * 64 + j], wcol[j], acc);
            out[(size_t)(n0 + rr) * 256 + tid] = acc;
        }
        __syncthreads();
    }
}

extern "C" void kernel_launch(void* const* d_in, const int* in_sizes, int n_in,
                              void* d_out, int out_size, void* d_ws, size_t ws_size,
                              hipStream_t stream)
{
    const float*  p    = (const float*)d_in[0];
    const float4* f    = (const float4*)d_in[1];
    const int*    gidx = (const int*)d_in[2];
    const float*  w1   = (const float*)d_in[3];
    const float*  g1   = (const float*)d_in[4];
    const float*  b1   = (const float*)d_in[5];
    const float*  w2   = (const float*)d_in[6];
    const float*  g2   = (const float*)d_in[7];
    const float*  b2   = (const float*)d_in[8];
    const float*  w3   = (const float*)d_in[9];
    const float*  gn   = (const float*)d_in[10];
    // d_in[11] = b_nbr: cancels exactly in the collapsed double-BN
    const float*  gp   = (const float*)d_in[12];
    const float*  bp   = (const float*)d_in[13];
    const float*  wp   = (const float*)d_in[14];
    float* out = (float*)d_out;
    float* ws  = (float*)d_ws;

    float* stats1 = ws;        float* scsh1 = ws + 32;
    float* stats2 = ws + 64;   float* scsh2 = ws + 128;
    float* stats3 = ws + 192;  float* scsh3 = ws + 320;
    float* pooled = ws + 1024;

    hipMemsetAsync(d_ws, 0, 2048, stream);
    k_stats1<<<2048, 256, 0, stream>>>(p, f, gidx, w1, stats1);
    k_finalize<<<1, 64, 0, stream>>>(stats1, g1, b1, scsh1, 16, 1.0f / (float)MROWS);
    k_stats2<<<2048, 256, 0, stream>>>(p, f, gidx, w1, w2, scsh1, stats2);
    k_finalize<<<1, 64, 0, stream>>>(stats2, g2, b2, scsh2, 32, 1.0f / (float)MROWS);
    k_pool2<<<3125, 256, 0, stream>>>(p, f, gidx, w1, w2, w3, scsh1, scsh2, stats3, pooled);
    k_fin3<<<1, 64, 0, stream>>>(stats3, gn, gp, bp, scsh3);
    k_head<<<1024, 256, 0, stream>>>(pooled, scsh3, wp, out);
}